// Round 4
// baseline (850.391 us; speedup 1.0000x reference)
//
#include <hip/hip_runtime.h>

#define T_SEQ 2048
#define HID   4096
#define NH    32
#define NKV   8
#define HD    128
#define QS    (NH*HD)        // 4096
#define KVS   (NKV*HD)       // 1024
#define QKVN  (QS + 2*KVS)   // 6144

typedef unsigned short u16;
typedef __attribute__((ext_vector_type(8))) __bf16 bf16x8;
typedef __attribute__((ext_vector_type(8))) unsigned short u16x8;
typedef __attribute__((ext_vector_type(4))) float f32x4;

__device__ __forceinline__ u16 f2bu(float x) {          // f32 -> bf16 (RNE)
  unsigned u = __builtin_bit_cast(unsigned, x);
  return (u16)((u + 0x7fffu + ((u >> 16) & 1u)) >> 16);
}
__device__ __forceinline__ float bu2f(u16 v) {
  unsigned u = ((unsigned)v) << 16;
  return __builtin_bit_cast(float, u);
}
__device__ __forceinline__ void gload16(const void* g, void* l) {
  __builtin_amdgcn_global_load_lds((const __attribute__((address_space(1))) void*)g,
                                   (__attribute__((address_space(3))) void*)l, 16, 0, 0);
}

// ---------------- f32 -> bf16 convert (8 elems/thread) ----------------
__global__ void k_cvt(const float* __restrict__ in, u16* __restrict__ out, int n8) {
  for (int i = blockIdx.x * blockDim.x + threadIdx.x; i < n8; i += gridDim.x * blockDim.x) {
    const float4* p = (const float4*)in + (size_t)i * 2;
    float4 a = p[0], b = p[1];
    u16x8 v;
    v[0]=f2bu(a.x); v[1]=f2bu(a.y); v[2]=f2bu(a.z); v[3]=f2bu(a.w);
    v[4]=f2bu(b.x); v[5]=f2bu(b.y); v[6]=f2bu(b.z); v[7]=f2bu(b.w);
    *((u16x8*)out + i) = v;
  }
}

// ------------- f32 [R][C] -> bf16 out[C][R] (transpose convert) -------------
__global__ void k_transcvt(const float* __restrict__ in, u16* __restrict__ out, int R, int C) {
  __shared__ float tile[32][33];
  int c0 = blockIdx.x * 32, r0 = blockIdx.y * 32;
  int tx = threadIdx.x & 31, ty = threadIdx.x >> 5;   // 32 x 8
#pragma unroll
  for (int g = 0; g < 4; ++g)
    tile[ty + g * 8][tx] = in[(size_t)(r0 + ty + g * 8) * C + c0 + tx];
  __syncthreads();
#pragma unroll
  for (int g = 0; g < 4; ++g) {
    int cc = g * 8 + ty;
    out[(size_t)(c0 + cc) * R + r0 + tx] = f2bu(tile[tx][cc]);
  }
}

// ------- bf16 GEMM: C[m,n] = sum_k A[m,k] * Bt[n,k]; C stride ldc -------
// 128x128 tile, BK=64, 4 waves (each 64x64), mfma_f32_16x16x32_bf16
// OUTF32=1 writes float (harness d_out is f32); else bf16.
template<int OUTF32>
__global__ __launch_bounds__(256, 2)
void k_gemm(const u16* __restrict__ A, const u16* __restrict__ Bt,
            void* __restrict__ C, int K, int ldc) {
  __shared__ u16 sA[128 * 64];
  __shared__ u16 sB[128 * 64];
  const int tid = threadIdx.x;
  const int w = tid >> 6, lane = tid & 63, lo = lane & 15, hi = lane >> 4;
  const int wr = w >> 1, wc = w & 1;
  const int bm = blockIdx.y * 128, bn = blockIdx.x * 128;
  f32x4 acc[4][4] = {};
  const int nk = K >> 6;
  for (int kt = 0; kt < nk; ++kt) {
    const int kbase = kt * 64;
#pragma unroll
    for (int i = 0; i < 4; ++i) {          // stage 16KB A + 16KB B
      int c = i * 256 + tid;
      int row = c >> 3, o8 = (c & 7) * 8;
      gload16(A + (size_t)(bm + row) * K + kbase + o8, sA + c * 8);
      gload16(Bt + (size_t)(bn + row) * K + kbase + o8, sB + c * 8);
    }
    __syncthreads();
#pragma unroll
    for (int kc = 0; kc < 2; ++kc) {
      bf16x8 af[4], bfr[4];
#pragma unroll
      for (int m = 0; m < 4; ++m)
        af[m] = *(const bf16x8*)(sA + (wr * 64 + m * 16 + lo) * 64 + kc * 32 + hi * 8);
#pragma unroll
      for (int n = 0; n < 4; ++n)
        bfr[n] = *(const bf16x8*)(sB + (wc * 64 + n * 16 + lo) * 64 + kc * 32 + hi * 8);
#pragma unroll
      for (int m = 0; m < 4; ++m)
#pragma unroll
        for (int n = 0; n < 4; ++n)
          acc[m][n] = __builtin_amdgcn_mfma_f32_16x16x32_bf16(af[m], bfr[n], acc[m][n], 0, 0, 0);
    }
    __syncthreads();
  }
#pragma unroll
  for (int m = 0; m < 4; ++m)
#pragma unroll
    for (int n = 0; n < 4; ++n) {
      int col = bn + wc * 64 + n * 16 + lo;
#pragma unroll
      for (int r = 0; r < 4; ++r) {
        int row = bm + wr * 64 + m * 16 + hi * 4 + r;
        float v = acc[m][n][r];
        if (OUTF32) ((float*)C)[(size_t)row * ldc + col] = v;
        else        ((u16*)C)[(size_t)row * ldc + col] = f2bu(v);
      }
    }
}

// -------- fused RMSNorm + RoPE; qkv[T][6144] -> q[h][t][d], k/v[kvh][t][d] --------
__global__ void k_normrope(const u16* __restrict__ qkv, const int* __restrict__ pos,
                           const float* __restrict__ qw, const float* __restrict__ kw,
                           u16* __restrict__ qb, u16* __restrict__ kb, u16* __restrict__ vb) {
  const int t = blockIdx.x;
  const int tid = threadIdx.x, w = tid >> 6, lane = tid & 63;
  const float p = (float)pos[t];
  const int d0 = lane * 2;
  const int j = d0 & 63;
  const float L2T_64 = 19.931568569324174f / 64.0f;   // log2(1e6)/64
  float ang0 = p * exp2f(-(float)j * L2T_64);
  float ang1 = p * exp2f(-(float)(j + 1) * L2T_64);
  float c0 = cosf(ang0), s0 = sinf(ang0);
  float c1 = cosf(ang1), s1 = sinf(ang1);
  const bool hiHalf = lane >= 32;
  for (int it = 0; it < 10; ++it) {
    int h = it * 4 + w;                        // 0..39 (32 q heads + 8 k heads)
    bool isq = h < NH;
    int base = t * QKVN + (isq ? h * HD : QS + (h - NH) * HD);
    float x0 = bu2f(qkv[base + d0]);
    float x1 = bu2f(qkv[base + d0 + 1]);
    float ss = x0 * x0 + x1 * x1;
#pragma unroll
    for (int off = 1; off < 64; off <<= 1) ss += __shfl_xor(ss, off);
    float inv = rsqrtf(ss * (1.0f / 128.0f) + 1e-6f);
    const float* nw = isq ? qw : kw;
    float y0 = x0 * inv * nw[d0];
    float y1 = x1 * inv * nw[d0 + 1];
    float z0 = __shfl_xor(y0, 32);             // partner element (d +/- 64)
    float z1 = __shfl_xor(y1, 32);
    float r0 = hiHalf ? (y0 * c0 + z0 * s0) : (y0 * c0 - z0 * s0);
    float r1 = hiHalf ? (y1 * c1 + z1 * s1) : (y1 * c1 - z1 * s1);
    u16* dst = isq ? (qb + ((size_t)h * T_SEQ + t) * HD)
                   : (kb + ((size_t)(h - NH) * T_SEQ + t) * HD);
    dst[d0] = f2bu(r0);
    dst[d0 + 1] = f2bu(r1);
  }
  for (int i = tid; i < KVS; i += 256) {       // v: plain cast copy
    int kvh = i >> 7, d = i & 127;
    vb[((size_t)kvh * T_SEQ + t) * HD + d] = qkv[t * QKVN + QS + KVS + i];
  }
}

// ---------------- causal GQA flash attention ----------------
// block = (q-block of 64 rows, head); 4 waves, wave = 16 q rows; KV tile = 32
__global__ __launch_bounds__(256, 2)
void k_attn(const u16* __restrict__ qb, const u16* __restrict__ kb,
            const u16* __restrict__ vb, u16* __restrict__ ao) {
  __shared__ u16 Ks[32 * 128];       // [kv][feat]
  __shared__ u16 Vt[128 * 32];       // [feat][kv]
  __shared__ u16 Ps[4][16 * 32];     // per-wave P
  const int h = blockIdx.y, kvh = h >> 2;
  const int q0 = blockIdx.x * 64;
  const int tid = threadIdx.x, w = tid >> 6, lane = tid & 63, lo = lane & 15, hi = lane >> 4;
  const int qr0 = q0 + w * 16;
  bf16x8 qf[4];
  const u16* Qp = qb + ((size_t)h * T_SEQ + qr0 + lo) * HD;
#pragma unroll
  for (int kc = 0; kc < 4; ++kc) qf[kc] = *(const bf16x8*)(Qp + kc * 32 + hi * 8);
  f32x4 o[8] = {};
  float mrow[4], ssum[4];
#pragma unroll
  for (int r = 0; r < 4; ++r) { mrow[r] = -1e30f; ssum[r] = 0.f; }
  const float scale = 0.08838834764831845f;   // 1/sqrt(128)
  const int nkt = blockIdx.x * 2 + 2;
  const u16* Kb = kb + (size_t)kvh * T_SEQ * HD;
  const u16* Vb = vb + (size_t)kvh * T_SEQ * HD;
  for (int kt = 0; kt < nkt; ++kt) {
#pragma unroll
    for (int i = 0; i < 2; ++i) {             // K tile: 8KB via global_load_lds
      int c = i * 256 + tid;
      int row = c >> 4, o8 = (c & 15) * 8;
      gload16(Kb + (size_t)(kt * 32 + row) * HD + o8, Ks + c * 8);
    }
    {                                          // V tile transposed via regs
      int vr = tid >> 3, vc0 = (tid & 7) * 16;
      const u16* vsrc = Vb + (size_t)(kt * 32 + vr) * HD + vc0;
      u16x8 v0 = *(const u16x8*)(vsrc);
      u16x8 v1 = *(const u16x8*)(vsrc + 8);
#pragma unroll
      for (int e = 0; e < 8; ++e) {
        Vt[(vc0 + e) * 32 + vr] = v0[e];
        Vt[(vc0 + 8 + e) * 32 + vr] = v1[e];
      }
    }
    __syncthreads();
    f32x4 sa[2] = {};
#pragma unroll
    for (int kc = 0; kc < 4; ++kc) {
      bf16x8 k0 = *(const bf16x8*)(Ks + (lo) * 128 + kc * 32 + hi * 8);
      bf16x8 k1 = *(const bf16x8*)(Ks + (16 + lo) * 128 + kc * 32 + hi * 8);
      sa[0] = __builtin_amdgcn_mfma_f32_16x16x32_bf16(qf[kc], k0, sa[0], 0, 0, 0);
      sa[1] = __builtin_amdgcn_mfma_f32_16x16x32_bf16(qf[kc], k1, sa[1], 0, 0, 0);
    }
    float pvv[2][4], pmax[4];
#pragma unroll
    for (int r = 0; r < 4; ++r) {
      int qi = qr0 + hi * 4 + r;
      int kj0 = kt * 32 + lo;
      float s0v = (kj0      <= qi) ? sa[0][r] * scale : -1e30f;
      float s1v = (kj0 + 16 <= qi) ? sa[1][r] * scale : -1e30f;
      pvv[0][r] = s0v; pvv[1][r] = s1v;
      float pm = fmaxf(s0v, s1v);
#pragma unroll
      for (int off = 1; off < 16; off <<= 1) pm = fmaxf(pm, __shfl_xor(pm, off));
      pmax[r] = pm;
    }
#pragma unroll
    for (int r = 0; r < 4; ++r) {
      float mnew = fmaxf(mrow[r], pmax[r]);
      float corr = __expf(mrow[r] - mnew);
      mrow[r] = mnew;
      float p0 = __expf(pvv[0][r] - mnew);
      float p1 = __expf(pvv[1][r] - mnew);
      pvv[0][r] = p0; pvv[1][r] = p1;
      float ps = p0 + p1;
#pragma unroll
      for (int off = 1; off < 16; off <<= 1) ps += __shfl_xor(ps, off);
      ssum[r] = ssum[r] * corr + ps;
#pragma unroll
      for (int nf = 0; nf < 8; ++nf) o[nf][r] *= corr;
    }
    u16* Pw = Ps[w];                            // wave-local P round-trip
#pragma unroll
    for (int n = 0; n < 2; ++n)
#pragma unroll
      for (int r = 0; r < 4; ++r)
        Pw[(hi * 4 + r) * 32 + n * 16 + lo] = f2bu(pvv[n][r]);
    bf16x8 pf = *(const bf16x8*)(Pw + lo * 32 + hi * 8);
#pragma unroll
    for (int nf = 0; nf < 8; ++nf) {
      bf16x8 vf = *(const bf16x8*)(Vt + (nf * 16 + lo) * 32 + hi * 8);
      o[nf] = __builtin_amdgcn_mfma_f32_16x16x32_bf16(pf, vf, o[nf], 0, 0, 0);
    }
    __syncthreads();
  }
#pragma unroll
  for (int r = 0; r < 4; ++r) ssum[r] = 1.0f / ssum[r];
#pragma unroll
  for (int nf = 0; nf < 8; ++nf)
#pragma unroll
    for (int r = 0; r < 4; ++r) {
      int row = qr0 + hi * 4 + r;
      ao[(size_t)row * HID + h * HD + nf * 16 + lo] = f2bu(o[nf][r] * ssum[r]);
    }
}

// ---------------- launch ----------------
// d_out is FLOAT32 (2048*4096 f32 = 32 MiB): used as bf16 scratch for hsb
// (lower 16 MiB) and qbuf (upper 16 MiB) before the final f32 GEMM overwrites
// the whole buffer. Workspace peak: 112 MiB (round-2/3 evidence: ws >= 120 MiB).
extern "C" void kernel_launch(void* const* d_in, const int* in_sizes, int n_in,
                              void* d_out, int out_size, void* d_ws, size_t ws_size,
                              hipStream_t stream) {
  (void)in_sizes; (void)n_in; (void)out_size; (void)ws_size;
  const int*   positions = (const int*)d_in[0];
  const float* hs   = (const float*)d_in[1];
  const float* wqkv = (const float*)d_in[2];
  const float* wo   = (const float*)d_in[3];
  const float* qnw  = (const float*)d_in[4];
  const float* knw  = (const float*)d_in[5];
  char* ws = (char*)d_ws;

  u16* hsb   = (u16*)d_out;                     // 16 MiB (d_out lower half)
  u16* qbuf  = (u16*)d_out + 8388608;           // 16 MiB (d_out upper half)
  u16* wqkvT = (u16*)(ws + 0);                  // 48 MiB (0 .. 50331648)
  u16* woT   = (u16*)(ws + 50331648);           // 32 MiB (50331648 .. 83886080)
  u16* qkvb  = (u16*)(ws + 83886080);           // 24 MiB (83886080 .. 109051904)
  u16* kbuf  = (u16*)(ws + 109051904);          //  4 MiB
  u16* vbuf  = (u16*)(ws + 113246208);          //  4 MiB (ends 117440512)
  u16* aob   = (u16*)(ws + 0);                  // 16 MiB (reuses dead wqkvT)

  k_cvt<<<2048, 256, 0, stream>>>(hs, hsb, (T_SEQ * HID) / 8);
  k_transcvt<<<dim3(QKVN / 32, HID / 32), 256, 0, stream>>>(wqkv, wqkvT, HID, QKVN);
  k_transcvt<<<dim3(HID / 32, QS / 32), 256, 0, stream>>>(wo, woT, QS, HID);
  k_gemm<0><<<dim3(QKVN / 128, T_SEQ / 128), 256, 0, stream>>>(hsb, wqkvT, qkvb, HID, QKVN);
  k_normrope<<<T_SEQ, 256, 0, stream>>>(qkvb, positions, qnw, knw, qbuf, kbuf, vbuf);
  k_attn<<<dim3(T_SEQ / 64, NH), 256, 0, stream>>>(qbuf, kbuf, vbuf, aob);
  k_gemm<1><<<dim3(HID / 128, T_SEQ / 128), 256, 0, stream>>>(aob, woT, d_out, QS, HID);
}

// Round 5
// 648.633 us; speedup vs baseline: 1.3111x; 1.3111x over previous
//
#include <hip/hip_runtime.h>

#define T_SEQ 2048
#define HID   4096
#define NH    32
#define NKV   8
#define HD    128
#define QS    (NH*HD)        // 4096
#define KVS   (NKV*HD)       // 1024
#define QKVN  (QS + 2*KVS)   // 6144

typedef unsigned short u16;
typedef __attribute__((ext_vector_type(8))) __bf16 bf16x8;
typedef __attribute__((ext_vector_type(8))) unsigned short u16x8;
typedef __attribute__((ext_vector_type(4))) unsigned short u16x4;
typedef __attribute__((ext_vector_type(4))) float f32x4;

__device__ __forceinline__ u16 f2bu(float x) {          // f32 -> bf16 (RNE)
  unsigned u = __builtin_bit_cast(unsigned, x);
  return (u16)((u + 0x7fffu + ((u >> 16) & 1u)) >> 16);
}
__device__ __forceinline__ float bu2f(u16 v) {
  unsigned u = ((unsigned)v) << 16;
  return __builtin_bit_cast(float, u);
}
__device__ __forceinline__ void gload16(const void* g, void* l) {
  __builtin_amdgcn_global_load_lds((const __attribute__((address_space(1))) void*)g,
                                   (__attribute__((address_space(3))) void*)l, 16, 0, 0);
}

// ---------------- f32 -> bf16 convert (8 elems/thread) ----------------
__global__ void k_cvt(const float* __restrict__ in, u16* __restrict__ out, int n8) {
  for (int i = blockIdx.x * blockDim.x + threadIdx.x; i < n8; i += gridDim.x * blockDim.x) {
    const float4* p = (const float4*)in + (size_t)i * 2;
    float4 a = p[0], b = p[1];
    u16x8 v;
    v[0]=f2bu(a.x); v[1]=f2bu(a.y); v[2]=f2bu(a.z); v[3]=f2bu(a.w);
    v[4]=f2bu(b.x); v[5]=f2bu(b.y); v[6]=f2bu(b.z); v[7]=f2bu(b.w);
    *((u16x8*)out + i) = v;
  }
}

// ------------- f32 [R][C] -> bf16 out[C][R] (transpose convert) -------------
__global__ void k_transcvt(const float* __restrict__ in, u16* __restrict__ out, int R, int C) {
  __shared__ float tile[32][33];
  int c0 = blockIdx.x * 32, r0 = blockIdx.y * 32;
  int tx = threadIdx.x & 31, ty = threadIdx.x >> 5;   // 32 x 8
#pragma unroll
  for (int g = 0; g < 4; ++g)
    tile[ty + g * 8][tx] = in[(size_t)(r0 + ty + g * 8) * C + c0 + tx];
  __syncthreads();
#pragma unroll
  for (int g = 0; g < 4; ++g) {
    int cc = g * 8 + ty;
    out[(size_t)(c0 + cc) * R + r0 + tx] = f2bu(tile[tx][cc]);
  }
}

// ------- bf16 GEMM: C[m,n] = sum_k A[m,k] * Bt[n,k]; C stride ldc -------
// 128x128 tile, BK=64, 4 waves (each 64x64), mfma_f32_16x16x32_bf16
// OUTF32=1 writes float (harness d_out is f32); else bf16.
template<int OUTF32>
__global__ __launch_bounds__(256, 2)
void k_gemm(const u16* __restrict__ A, const u16* __restrict__ Bt,
            void* __restrict__ C, int K, int ldc) {
  __shared__ u16 sA[128 * 64];
  __shared__ u16 sB[128 * 64];
  const int tid = threadIdx.x;
  const int w = tid >> 6, lane = tid & 63, lo = lane & 15, hi = lane >> 4;
  const int wr = w >> 1, wc = w & 1;
  const int bm = blockIdx.y * 128, bn = blockIdx.x * 128;
  f32x4 acc[4][4] = {};
  const int nk = K >> 6;
  for (int kt = 0; kt < nk; ++kt) {
    const int kbase = kt * 64;
#pragma unroll
    for (int i = 0; i < 4; ++i) {          // stage 16KB A + 16KB B
      int c = i * 256 + tid;
      int row = c >> 3, o8 = (c & 7) * 8;
      gload16(A + (size_t)(bm + row) * K + kbase + o8, sA + c * 8);
      gload16(Bt + (size_t)(bn + row) * K + kbase + o8, sB + c * 8);
    }
    __syncthreads();
#pragma unroll
    for (int kc = 0; kc < 2; ++kc) {
      bf16x8 af[4], bfr[4];
#pragma unroll
      for (int m = 0; m < 4; ++m)
        af[m] = *(const bf16x8*)(sA + (wr * 64 + m * 16 + lo) * 64 + kc * 32 + hi * 8);
#pragma unroll
      for (int n = 0; n < 4; ++n)
        bfr[n] = *(const bf16x8*)(sB + (wc * 64 + n * 16 + lo) * 64 + kc * 32 + hi * 8);
#pragma unroll
      for (int m = 0; m < 4; ++m)
#pragma unroll
        for (int n = 0; n < 4; ++n)
          acc[m][n] = __builtin_amdgcn_mfma_f32_16x16x32_bf16(af[m], bfr[n], acc[m][n], 0, 0, 0);
    }
    __syncthreads();
  }
#pragma unroll
  for (int m = 0; m < 4; ++m)
#pragma unroll
    for (int n = 0; n < 4; ++n) {
      int col = bn + wc * 64 + n * 16 + lo;
#pragma unroll
      for (int r = 0; r < 4; ++r) {
        int row = bm + wr * 64 + m * 16 + hi * 4 + r;
        float v = acc[m][n][r];
        if (OUTF32) ((float*)C)[(size_t)row * ldc + col] = v;
        else        ((u16*)C)[(size_t)row * ldc + col] = f2bu(v);
      }
    }
}

// -------- fused RMSNorm + RoPE; qkv[T][6144] -> q[h][t][d], k/v[kvh][t][d] --------
__global__ void k_normrope(const u16* __restrict__ qkv, const int* __restrict__ pos,
                           const float* __restrict__ qw, const float* __restrict__ kw,
                           u16* __restrict__ qb, u16* __restrict__ kb, u16* __restrict__ vb) {
  const int t = blockIdx.x;
  const int tid = threadIdx.x, w = tid >> 6, lane = tid & 63;
  const float p = (float)pos[t];
  const int d0 = lane * 2;
  const int j = d0 & 63;
  const float L2T_64 = 19.931568569324174f / 64.0f;   // log2(1e6)/64
  float ang0 = p * exp2f(-(float)j * L2T_64);
  float ang1 = p * exp2f(-(float)(j + 1) * L2T_64);
  float c0 = cosf(ang0), s0 = sinf(ang0);
  float c1 = cosf(ang1), s1 = sinf(ang1);
  const bool hiHalf = lane >= 32;
  for (int it = 0; it < 10; ++it) {
    int h = it * 4 + w;                        // 0..39 (32 q heads + 8 k heads)
    bool isq = h < NH;
    int base = t * QKVN + (isq ? h * HD : QS + (h - NH) * HD);
    float x0 = bu2f(qkv[base + d0]);
    float x1 = bu2f(qkv[base + d0 + 1]);
    float ss = x0 * x0 + x1 * x1;
#pragma unroll
    for (int off = 1; off < 64; off <<= 1) ss += __shfl_xor(ss, off);
    float inv = rsqrtf(ss * (1.0f / 128.0f) + 1e-6f);
    const float* nw = isq ? qw : kw;
    float y0 = x0 * inv * nw[d0];
    float y1 = x1 * inv * nw[d0 + 1];
    float z0 = __shfl_xor(y0, 32);             // partner element (d +/- 64)
    float z1 = __shfl_xor(y1, 32);
    float r0 = hiHalf ? (y0 * c0 + z0 * s0) : (y0 * c0 - z0 * s0);
    float r1 = hiHalf ? (y1 * c1 + z1 * s1) : (y1 * c1 - z1 * s1);
    u16* dst = isq ? (qb + ((size_t)h * T_SEQ + t) * HD)
                   : (kb + ((size_t)(h - NH) * T_SEQ + t) * HD);
    dst[d0] = f2bu(r0);
    dst[d0 + 1] = f2bu(r1);
  }
  for (int i = tid; i < KVS; i += 256) {       // v: plain cast copy
    int kvh = i >> 7, d = i & 127;
    vb[((size_t)kvh * T_SEQ + t) * HD + d] = qkv[t * QKVN + QS + KVS + i];
  }
}

// ---------------- causal GQA flash attention (v2) ----------------
// block = (64 q rows, head); 4 waves x 16 q rows; KV tile = 64.
// All LDS tiles 16B-group XOR-swizzled: group g stored at g' = g ^ (row&7),
// so b128 read phases (8 consecutive lanes, lo&7 varying) hit 8 distinct
// 16B slots -> conflict-free. K staged via global_load_lds with the INVERSE
// swizzle applied to the per-lane global source (linear LDS dest).
__global__ __launch_bounds__(256, 4)
void k_attn(const u16* __restrict__ qb, const u16* __restrict__ kb,
            const u16* __restrict__ vb, u16* __restrict__ ao) {
  __shared__ u16 Ks[64 * 128];       // [kv][feat]  (swizzled groups)
  __shared__ u16 Vt[128 * 64];       // [feat][kv]  (swizzled groups)
  __shared__ u16 Ps[4][16 * 64];     // per-wave P  (swizzled groups)
  const int h = blockIdx.y, kvh = h >> 2;
  const int q0 = blockIdx.x * 64;
  const int tid = threadIdx.x, w = tid >> 6, lane = tid & 63, lo = lane & 15, hi = lane >> 4;
  const int lo7 = lane & 7;
  const int qr0 = q0 + w * 16;
  bf16x8 qf[4];
  const u16* Qp = qb + ((size_t)h * T_SEQ + qr0 + lo) * HD;
#pragma unroll
  for (int kc = 0; kc < 4; ++kc) qf[kc] = *(const bf16x8*)(Qp + kc * 32 + hi * 8);
  f32x4 o[8] = {};
  float mrow[4], ssum[4];
#pragma unroll
  for (int r = 0; r < 4; ++r) { mrow[r] = -1e30f; ssum[r] = 0.f; }
  const float scale = 0.08838834764831845f;   // 1/sqrt(128)
  const int nkt = blockIdx.x + 1;
  const u16* Kb = kb + (size_t)kvh * T_SEQ * HD;
  const u16* Vb = vb + (size_t)kvh * T_SEQ * HD;
  // K staging: row within 16-row chunk + inverse-swizzled source group
  const int krow = tid >> 4;                       // 0..15
  const int kg = (tid & 15) ^ (krow & 7);          // source 16B-group (0..15)
  // V transpose: thread handles kv chunk (4 rows) x 8 feats
  const int vkvc = tid & 15, vfc = tid >> 4;       // kv chunk 0..15, feat chunk 0..15

  for (int kt = 0; kt < nkt; ++kt) {
#pragma unroll
    for (int i = 0; i < 4; ++i)                     // K tile: 16KB, pre-swizzled src
      gload16(Kb + (size_t)(kt * 64 + i * 16 + krow) * HD + kg * 8,
              Ks + i * 2048 + tid * 8);
    {                                               // V tile -> Vt[feat][kv] swizzled
      u16x8 vv0 = *(const u16x8*)(Vb + (size_t)(kt * 64 + vkvc * 4 + 0) * HD + vfc * 8);
      u16x8 vv1 = *(const u16x8*)(Vb + (size_t)(kt * 64 + vkvc * 4 + 1) * HD + vfc * 8);
      u16x8 vv2 = *(const u16x8*)(Vb + (size_t)(kt * 64 + vkvc * 4 + 2) * HD + vfc * 8);
      u16x8 vv3 = *(const u16x8*)(Vb + (size_t)(kt * 64 + vkvc * 4 + 3) * HD + vfc * 8);
#pragma unroll
      for (int e = 0; e < 8; ++e) {
        int feat = vfc * 8 + e;
        int gp = (vkvc >> 1) ^ (feat & 7);
        u16x4 pk; pk[0] = vv0[e]; pk[1] = vv1[e]; pk[2] = vv2[e]; pk[3] = vv3[e];
        *(u16x4*)(Vt + feat * 64 + gp * 8 + (vkvc & 1) * 4) = pk;
      }
    }
    __syncthreads();
    // ---- QK^T: 4 n-tiles of 16 kv ----
    f32x4 sa[4] = {};
#pragma unroll
    for (int kc = 0; kc < 4; ++kc) {
#pragma unroll
      for (int n = 0; n < 4; ++n) {
        int row = n * 16 + lo;
        bf16x8 kf = *(const bf16x8*)(Ks + row * 128 + (((kc * 4 + hi) ^ lo7) * 8));
        sa[n] = __builtin_amdgcn_mfma_f32_16x16x32_bf16(qf[kc], kf, sa[n], 0, 0, 0);
      }
    }
    // ---- mask + online softmax ----
    float pvv[4][4], pmax[4];
#pragma unroll
    for (int r = 0; r < 4; ++r) {
      int qi = qr0 + hi * 4 + r;
      float pm = -1e30f;
#pragma unroll
      for (int n = 0; n < 4; ++n) {
        int kj = kt * 64 + n * 16 + lo;
        float sv = (kj <= qi) ? sa[n][r] * scale : -1e30f;
        pvv[n][r] = sv;
        pm = fmaxf(pm, sv);
      }
#pragma unroll
      for (int off = 1; off < 16; off <<= 1) pm = fmaxf(pm, __shfl_xor(pm, off));
      pmax[r] = pm;
    }
#pragma unroll
    for (int r = 0; r < 4; ++r) {
      float mnew = fmaxf(mrow[r], pmax[r]);
      float corr = __expf(mrow[r] - mnew);
      mrow[r] = mnew;
      float ps = 0.f;
#pragma unroll
      for (int n = 0; n < 4; ++n) {
        float p = __expf(pvv[n][r] - mnew);
        pvv[n][r] = p; ps += p;
      }
#pragma unroll
      for (int off = 1; off < 16; off <<= 1) ps += __shfl_xor(ps, off);
      ssum[r] = ssum[r] * corr + ps;
#pragma unroll
      for (int nf = 0; nf < 8; ++nf) o[nf][r] *= corr;
    }
    // ---- P -> LDS (swizzled), wave-local ----
    u16* Pw = Ps[w];
#pragma unroll
    for (int n = 0; n < 4; ++n) {
      int gcol = n * 2 + (lo >> 3);
#pragma unroll
      for (int r = 0; r < 4; ++r) {
        int row = hi * 4 + r;
        Pw[row * 64 + ((gcol ^ (row & 7)) * 8) + lo7] = f2bu(pvv[n][r]);
      }
    }
    // ---- PV ----
#pragma unroll
    for (int ks = 0; ks < 2; ++ks) {
      bf16x8 pf = *(const bf16x8*)(Pw + lo * 64 + (((ks * 4 + hi) ^ lo7) * 8));
#pragma unroll
      for (int nf = 0; nf < 8; ++nf) {
        int feat = nf * 16 + lo;
        bf16x8 vf = *(const bf16x8*)(Vt + feat * 64 + (((ks * 4 + hi) ^ lo7) * 8));
        o[nf] = __builtin_amdgcn_mfma_f32_16x16x32_bf16(pf, vf, o[nf], 0, 0, 0);
      }
    }
    __syncthreads();
  }
#pragma unroll
  for (int r = 0; r < 4; ++r) ssum[r] = 1.0f / ssum[r];
#pragma unroll
  for (int nf = 0; nf < 8; ++nf)
#pragma unroll
    for (int r = 0; r < 4; ++r) {
      int row = qr0 + hi * 4 + r;
      ao[(size_t)row * HID + h * HD + nf * 16 + lo] = f2bu(o[nf][r] * ssum[r]);
    }
}

// ---------------- launch ----------------
// d_out is FLOAT32 (2048*4096 f32 = 32 MiB): used as bf16 scratch for hsb
// (lower 16 MiB) and qbuf (upper 16 MiB) before the final f32 GEMM overwrites
// the whole buffer. Workspace peak: 112 MiB.
extern "C" void kernel_launch(void* const* d_in, const int* in_sizes, int n_in,
                              void* d_out, int out_size, void* d_ws, size_t ws_size,
                              hipStream_t stream) {
  (void)in_sizes; (void)n_in; (void)out_size; (void)ws_size;
  const int*   positions = (const int*)d_in[0];
  const float* hs   = (const float*)d_in[1];
  const float* wqkv = (const float*)d_in[2];
  const float* wo   = (const float*)d_in[3];
  const float* qnw  = (const float*)d_in[4];
  const float* knw  = (const float*)d_in[5];
  char* ws = (char*)d_ws;

  u16* hsb   = (u16*)d_out;                     // 16 MiB (d_out lower half)
  u16* qbuf  = (u16*)d_out + 8388608;           // 16 MiB (d_out upper half)
  u16* wqkvT = (u16*)(ws + 0);                  // 48 MiB (0 .. 50331648)
  u16* woT   = (u16*)(ws + 50331648);           // 32 MiB (50331648 .. 83886080)
  u16* qkvb  = (u16*)(ws + 83886080);           // 24 MiB (83886080 .. 109051904)
  u16* kbuf  = (u16*)(ws + 109051904);          //  4 MiB
  u16* vbuf  = (u16*)(ws + 113246208);          //  4 MiB (ends 117440512)
  u16* aob   = (u16*)(ws + 0);                  // 16 MiB (reuses dead wqkvT)

  k_cvt<<<2048, 256, 0, stream>>>(hs, hsb, (T_SEQ * HID) / 8);
  k_transcvt<<<dim3(QKVN / 32, HID / 32), 256, 0, stream>>>(wqkv, wqkvT, HID, QKVN);
  k_transcvt<<<dim3(HID / 32, QS / 32), 256, 0, stream>>>(wo, woT, QS, HID);
  k_gemm<0><<<dim3(QKVN / 128, T_SEQ / 128), 256, 0, stream>>>(hsb, wqkvT, qkvb, HID, QKVN);
  k_normrope<<<T_SEQ, 256, 0, stream>>>(qkvb, positions, qnw, knw, qbuf, kbuf, vbuf);
  k_attn<<<dim3(T_SEQ / 64, NH), 256, 0, stream>>>(qbuf, kbuf, vbuf, aob);
  k_gemm<1><<<dim3(HID / 128, T_SEQ / 128), 256, 0, stream>>>(aob, woT, d_out, QS, HID);
}

// Round 6
// 593.399 us; speedup vs baseline: 1.4331x; 1.0931x over previous
//
#include <hip/hip_runtime.h>

#define T_SEQ 2048
#define HID   4096
#define NH    32
#define NKV   8
#define HD    128
#define QS    (NH*HD)        // 4096
#define KVS   (NKV*HD)       // 1024
#define QKVN  (QS + 2*KVS)   // 6144

typedef unsigned short u16;
typedef __attribute__((ext_vector_type(8))) __bf16 bf16x8;
typedef __attribute__((ext_vector_type(8))) unsigned short u16x8;
typedef __attribute__((ext_vector_type(4))) unsigned short u16x4;
typedef __attribute__((ext_vector_type(4))) float f32x4;

__device__ __forceinline__ u16 f2bu(float x) {          // f32 -> bf16 (RNE)
  unsigned u = __builtin_bit_cast(unsigned, x);
  return (u16)((u + 0x7fffu + ((u >> 16) & 1u)) >> 16);
}
__device__ __forceinline__ float bu2f(u16 v) {
  unsigned u = ((unsigned)v) << 16;
  return __builtin_bit_cast(float, u);
}
__device__ __forceinline__ void gload16(const void* g, void* l) {
  __builtin_amdgcn_global_load_lds((const __attribute__((address_space(1))) void*)g,
                                   (__attribute__((address_space(3))) void*)l, 16, 0, 0);
}

// ---------------- f32 -> bf16 convert (8 elems/thread) ----------------
__global__ void k_cvt(const float* __restrict__ in, u16* __restrict__ out, int n8) {
  for (int i = blockIdx.x * blockDim.x + threadIdx.x; i < n8; i += gridDim.x * blockDim.x) {
    const float4* p = (const float4*)in + (size_t)i * 2;
    float4 a = p[0], b = p[1];
    u16x8 v;
    v[0]=f2bu(a.x); v[1]=f2bu(a.y); v[2]=f2bu(a.z); v[3]=f2bu(a.w);
    v[4]=f2bu(b.x); v[5]=f2bu(b.y); v[6]=f2bu(b.z); v[7]=f2bu(b.w);
    *((u16x8*)out + i) = v;
  }
}

// ------------- f32 [R][C] -> bf16 out[C][R] (transpose convert, 64x64) -------------
// load: float4 per lane, 64B-contiguous per 4-lane group; store: u16x8 pairs,
// 4-lane groups cover one 128B-contiguous out segment.
__global__ void k_transcvt(const float* __restrict__ in, u16* __restrict__ out, int R, int C) {
  __shared__ float tile[64][65];
  const int c0 = blockIdx.x * 64, r0 = blockIdx.y * 64;
  const int tid = threadIdx.x;
  const int row = tid >> 2, c4 = (tid & 3) * 4;
#pragma unroll
  for (int j = 0; j < 4; ++j) {
    float4 a = *(const float4*)(in + (size_t)(r0 + row) * C + c0 + c4 + j * 16);
    tile[row][c4 + j * 16 + 0] = a.x;
    tile[row][c4 + j * 16 + 1] = a.y;
    tile[row][c4 + j * 16 + 2] = a.z;
    tile[row][c4 + j * 16 + 3] = a.w;
  }
  __syncthreads();
  const int col = tid >> 2, rq = (tid & 3) * 16;
  u16x8 v0, v1;
#pragma unroll
  for (int j = 0; j < 8; ++j) v0[j] = f2bu(tile[rq + j][col]);
#pragma unroll
  for (int j = 0; j < 8; ++j) v1[j] = f2bu(tile[rq + 8 + j][col]);
  u16* dst = out + (size_t)(c0 + col) * R + r0 + rq;
  *(u16x8*)(dst) = v0;
  *(u16x8*)(dst + 8) = v1;
}

// ------- bf16 GEMM: C[m,n] = sum_k A[m,k] * Bt[n,k]; C stride ldc -------
// 128x128 tile, BK=64, 4 waves (each 64x64), mfma_f32_16x16x32_bf16
// OUTF32=1 writes float (harness d_out is f32); else bf16.
template<int OUTF32>
__global__ __launch_bounds__(256, 2)
void k_gemm(const u16* __restrict__ A, const u16* __restrict__ Bt,
            void* __restrict__ C, int K, int ldc) {
  __shared__ u16 sA[128 * 64];
  __shared__ u16 sB[128 * 64];
  const int tid = threadIdx.x;
  const int w = tid >> 6, lane = tid & 63, lo = lane & 15, hi = lane >> 4;
  const int wr = w >> 1, wc = w & 1;
  const int bm = blockIdx.y * 128, bn = blockIdx.x * 128;
  f32x4 acc[4][4] = {};
  const int nk = K >> 6;
  for (int kt = 0; kt < nk; ++kt) {
    const int kbase = kt * 64;
#pragma unroll
    for (int i = 0; i < 4; ++i) {          // stage 16KB A + 16KB B
      int c = i * 256 + tid;
      int row = c >> 3, o8 = (c & 7) * 8;
      gload16(A + (size_t)(bm + row) * K + kbase + o8, sA + c * 8);
      gload16(Bt + (size_t)(bn + row) * K + kbase + o8, sB + c * 8);
    }
    __syncthreads();
#pragma unroll
    for (int kc = 0; kc < 2; ++kc) {
      bf16x8 af[4], bfr[4];
#pragma unroll
      for (int m = 0; m < 4; ++m)
        af[m] = *(const bf16x8*)(sA + (wr * 64 + m * 16 + lo) * 64 + kc * 32 + hi * 8);
#pragma unroll
      for (int n = 0; n < 4; ++n)
        bfr[n] = *(const bf16x8*)(sB + (wc * 64 + n * 16 + lo) * 64 + kc * 32 + hi * 8);
#pragma unroll
      for (int m = 0; m < 4; ++m)
#pragma unroll
        for (int n = 0; n < 4; ++n)
          acc[m][n] = __builtin_amdgcn_mfma_f32_16x16x32_bf16(af[m], bfr[n], acc[m][n], 0, 0, 0);
    }
    __syncthreads();
  }
#pragma unroll
  for (int m = 0; m < 4; ++m)
#pragma unroll
    for (int n = 0; n < 4; ++n) {
      int col = bn + wc * 64 + n * 16 + lo;
#pragma unroll
      for (int r = 0; r < 4; ++r) {
        int row = bm + wr * 64 + m * 16 + hi * 4 + r;
        float v = acc[m][n][r];
        if (OUTF32) ((float*)C)[(size_t)row * ldc + col] = v;
        else        ((u16*)C)[(size_t)row * ldc + col] = f2bu(v);
      }
    }
}

// -------- fused RMSNorm + RoPE; qkv[T][6144] -> q[h][t][d], k/v[kvh][t][d] --------
__global__ void k_normrope(const u16* __restrict__ qkv, const int* __restrict__ pos,
                           const float* __restrict__ qw, const float* __restrict__ kw,
                           u16* __restrict__ qb, u16* __restrict__ kb, u16* __restrict__ vb) {
  const int t = blockIdx.x;
  const int tid = threadIdx.x, w = tid >> 6, lane = tid & 63;
  const float p = (float)pos[t];
  const int d0 = lane * 2;
  const int j = d0 & 63;
  const float L2T_64 = 19.931568569324174f / 64.0f;   // log2(1e6)/64
  float ang0 = p * exp2f(-(float)j * L2T_64);
  float ang1 = p * exp2f(-(float)(j + 1) * L2T_64);
  float c0 = cosf(ang0), s0 = sinf(ang0);
  float c1 = cosf(ang1), s1 = sinf(ang1);
  const bool hiHalf = lane >= 32;
  for (int it = 0; it < 10; ++it) {
    int h = it * 4 + w;                        // 0..39 (32 q heads + 8 k heads)
    bool isq = h < NH;
    int base = t * QKVN + (isq ? h * HD : QS + (h - NH) * HD);
    float x0 = bu2f(qkv[base + d0]);
    float x1 = bu2f(qkv[base + d0 + 1]);
    float ss = x0 * x0 + x1 * x1;
#pragma unroll
    for (int off = 1; off < 64; off <<= 1) ss += __shfl_xor(ss, off);
    float inv = rsqrtf(ss * (1.0f / 128.0f) + 1e-6f);
    const float* nw = isq ? qw : kw;
    float y0 = x0 * inv * nw[d0];
    float y1 = x1 * inv * nw[d0 + 1];
    float z0 = __shfl_xor(y0, 32);             // partner element (d +/- 64)
    float z1 = __shfl_xor(y1, 32);
    float r0 = hiHalf ? (y0 * c0 + z0 * s0) : (y0 * c0 - z0 * s0);
    float r1 = hiHalf ? (y1 * c1 + z1 * s1) : (y1 * c1 - z1 * s1);
    u16* dst = isq ? (qb + ((size_t)h * T_SEQ + t) * HD)
                   : (kb + ((size_t)(h - NH) * T_SEQ + t) * HD);
    dst[d0] = f2bu(r0);
    dst[d0 + 1] = f2bu(r1);
  }
  for (int i = tid; i < KVS; i += 256) {       // v: plain cast copy
    int kvh = i >> 7, d = i & 127;
    vb[((size_t)kvh * T_SEQ + t) * HD + d] = qkv[t * QKVN + QS + KVS + i];
  }
}

// ---------------- causal GQA flash attention (v3: balanced pairs) ----------------
// block = (pair of q-blocks, head); blockIdx.x in [0,16): processes q-block
// blockIdx.x then 31-blockIdx.x sequentially -> uniform 33 KV tiles per block.
// 4 waves x 16 q rows; KV tile = 64. LDS 16B-group XOR swizzle throughout.
__global__ __launch_bounds__(256, 4)
void k_attn(const u16* __restrict__ qb, const u16* __restrict__ kb,
            const u16* __restrict__ vb, u16* __restrict__ ao) {
  __shared__ u16 Ks[64 * 128];       // [kv][feat]  (swizzled groups)
  __shared__ u16 Vt[128 * 64];       // [feat][kv]  (swizzled groups)
  __shared__ u16 Ps[4][16 * 64];     // per-wave P  (swizzled groups)
  const int h = blockIdx.y, kvh = h >> 2;
  const int tid = threadIdx.x, w = tid >> 6, lane = tid & 63, lo = lane & 15, hi = lane >> 4;
  const int lo7 = lane & 7;
  const float scale = 0.08838834764831845f;   // 1/sqrt(128)
  const u16* Kb = kb + (size_t)kvh * T_SEQ * HD;
  const u16* Vb = vb + (size_t)kvh * T_SEQ * HD;
  // K staging: row within 16-row chunk + inverse-swizzled source group
  const int krow = tid >> 4;                       // 0..15
  const int kg = (tid & 15) ^ (krow & 7);          // source 16B-group (0..15)
  // V transpose: thread handles kv chunk (4 rows) x 8 feats
  const int vkvc = tid & 15, vfc = tid >> 4;       // kv chunk 0..15, feat chunk 0..15

  for (int item = 0; item < 2; ++item) {
    const int xb = item == 0 ? blockIdx.x : 31 - blockIdx.x;
    const int q0 = xb * 64;
    const int nkt = xb + 1;
    const int qr0 = q0 + w * 16;
    bf16x8 qf[4];
    const u16* Qp = qb + ((size_t)h * T_SEQ + qr0 + lo) * HD;
#pragma unroll
    for (int kc = 0; kc < 4; ++kc) qf[kc] = *(const bf16x8*)(Qp + kc * 32 + hi * 8);
    f32x4 o[8] = {};
    float mrow[4], ssum[4];
#pragma unroll
    for (int r = 0; r < 4; ++r) { mrow[r] = -1e30f; ssum[r] = 0.f; }

    for (int kt = 0; kt < nkt; ++kt) {
#pragma unroll
      for (int i = 0; i < 4; ++i)                   // K tile: 16KB, pre-swizzled src
        gload16(Kb + (size_t)(kt * 64 + i * 16 + krow) * HD + kg * 8,
                Ks + i * 2048 + tid * 8);
      {                                             // V tile -> Vt[feat][kv] swizzled
        u16x8 vv0 = *(const u16x8*)(Vb + (size_t)(kt * 64 + vkvc * 4 + 0) * HD + vfc * 8);
        u16x8 vv1 = *(const u16x8*)(Vb + (size_t)(kt * 64 + vkvc * 4 + 1) * HD + vfc * 8);
        u16x8 vv2 = *(const u16x8*)(Vb + (size_t)(kt * 64 + vkvc * 4 + 2) * HD + vfc * 8);
        u16x8 vv3 = *(const u16x8*)(Vb + (size_t)(kt * 64 + vkvc * 4 + 3) * HD + vfc * 8);
#pragma unroll
        for (int e = 0; e < 8; ++e) {
          int feat = vfc * 8 + e;
          int gp = (vkvc >> 1) ^ (feat & 7);
          u16x4 pk; pk[0] = vv0[e]; pk[1] = vv1[e]; pk[2] = vv2[e]; pk[3] = vv3[e];
          *(u16x4*)(Vt + feat * 64 + gp * 8 + (vkvc & 1) * 4) = pk;
        }
      }
      __syncthreads();
      // ---- QK^T: 4 n-tiles of 16 kv ----
      f32x4 sa[4] = {};
#pragma unroll
      for (int kc = 0; kc < 4; ++kc) {
#pragma unroll
        for (int n = 0; n < 4; ++n) {
          int row = n * 16 + lo;
          bf16x8 kf = *(const bf16x8*)(Ks + row * 128 + (((kc * 4 + hi) ^ lo7) * 8));
          sa[n] = __builtin_amdgcn_mfma_f32_16x16x32_bf16(qf[kc], kf, sa[n], 0, 0, 0);
        }
      }
      // ---- mask + online softmax ----
      float pvv[4][4], pmax[4];
#pragma unroll
      for (int r = 0; r < 4; ++r) {
        int qi = qr0 + hi * 4 + r;
        float pm = -1e30f;
#pragma unroll
        for (int n = 0; n < 4; ++n) {
          int kj = kt * 64 + n * 16 + lo;
          float sv = (kj <= qi) ? sa[n][r] * scale : -1e30f;
          pvv[n][r] = sv;
          pm = fmaxf(pm, sv);
        }
#pragma unroll
        for (int off = 1; off < 16; off <<= 1) pm = fmaxf(pm, __shfl_xor(pm, off));
        pmax[r] = pm;
      }
#pragma unroll
      for (int r = 0; r < 4; ++r) {
        float mnew = fmaxf(mrow[r], pmax[r]);
        float corr = __expf(mrow[r] - mnew);
        mrow[r] = mnew;
        float ps = 0.f;
#pragma unroll
        for (int n = 0; n < 4; ++n) {
          float p = __expf(pvv[n][r] - mnew);
          pvv[n][r] = p; ps += p;
        }
#pragma unroll
        for (int off = 1; off < 16; off <<= 1) ps += __shfl_xor(ps, off);
        ssum[r] = ssum[r] * corr + ps;
#pragma unroll
        for (int nf = 0; nf < 8; ++nf) o[nf][r] *= corr;
      }
      // ---- P -> LDS (swizzled), wave-local ----
      u16* Pw = Ps[w];
#pragma unroll
      for (int n = 0; n < 4; ++n) {
        int gcol = n * 2 + (lo >> 3);
#pragma unroll
        for (int r = 0; r < 4; ++r) {
          int row = hi * 4 + r;
          Pw[row * 64 + ((gcol ^ (row & 7)) * 8) + lo7] = f2bu(pvv[n][r]);
        }
      }
      // ---- PV ----
#pragma unroll
      for (int ks = 0; ks < 2; ++ks) {
        bf16x8 pf = *(const bf16x8*)(Pw + lo * 64 + (((ks * 4 + hi) ^ lo7) * 8));
#pragma unroll
        for (int nf = 0; nf < 8; ++nf) {
          int feat = nf * 16 + lo;
          bf16x8 vf = *(const bf16x8*)(Vt + feat * 64 + (((ks * 4 + hi) ^ lo7) * 8));
          o[nf] = __builtin_amdgcn_mfma_f32_16x16x32_bf16(pf, vf, o[nf], 0, 0, 0);
        }
      }
      __syncthreads();
    }
#pragma unroll
    for (int r = 0; r < 4; ++r) ssum[r] = 1.0f / ssum[r];
#pragma unroll
    for (int nf = 0; nf < 8; ++nf)
#pragma unroll
      for (int r = 0; r < 4; ++r) {
        int row = qr0 + hi * 4 + r;
        ao[(size_t)row * HID + h * HD + nf * 16 + lo] = f2bu(o[nf][r] * ssum[r]);
      }
  }
}

// ---------------- launch ----------------
// d_out is FLOAT32 (2048*4096 f32 = 32 MiB): used as bf16 scratch for hsb
// (lower 16 MiB) and qbuf (upper 16 MiB) before the final f32 GEMM overwrites
// the whole buffer. Workspace peak: 112 MiB.
extern "C" void kernel_launch(void* const* d_in, const int* in_sizes, int n_in,
                              void* d_out, int out_size, void* d_ws, size_t ws_size,
                              hipStream_t stream) {
  (void)in_sizes; (void)n_in; (void)out_size; (void)ws_size;
  const int*   positions = (const int*)d_in[0];
  const float* hs   = (const float*)d_in[1];
  const float* wqkv = (const float*)d_in[2];
  const float* wo   = (const float*)d_in[3];
  const float* qnw  = (const float*)d_in[4];
  const float* knw  = (const float*)d_in[5];
  char* ws = (char*)d_ws;

  u16* hsb   = (u16*)d_out;                     // 16 MiB (d_out lower half)
  u16* qbuf  = (u16*)d_out + 8388608;           // 16 MiB (d_out upper half)
  u16* wqkvT = (u16*)(ws + 0);                  // 48 MiB (0 .. 50331648)
  u16* woT   = (u16*)(ws + 50331648);           // 32 MiB (50331648 .. 83886080)
  u16* qkvb  = (u16*)(ws + 83886080);           // 24 MiB (83886080 .. 109051904)
  u16* kbuf  = (u16*)(ws + 109051904);          //  4 MiB
  u16* vbuf  = (u16*)(ws + 113246208);          //  4 MiB (ends 117440512)
  u16* aob   = (u16*)(ws + 0);                  // 16 MiB (reuses dead wqkvT)

  k_cvt<<<2048, 256, 0, stream>>>(hs, hsb, (T_SEQ * HID) / 8);
  k_transcvt<<<dim3(QKVN / 64, HID / 64), 256, 0, stream>>>(wqkv, wqkvT, HID, QKVN);
  k_transcvt<<<dim3(HID / 64, QS / 64), 256, 0, stream>>>(wo, woT, QS, HID);
  k_gemm<0><<<dim3(QKVN / 128, T_SEQ / 128), 256, 0, stream>>>(hsb, wqkvT, qkvb, HID, QKVN);
  k_normrope<<<T_SEQ, 256, 0, stream>>>(qkvb, positions, qnw, knw, qbuf, kbuf, vbuf);
  k_attn<<<dim3(16, NH), 256, 0, stream>>>(qbuf, kbuf, vbuf, aob);
  k_gemm<1><<<dim3(HID / 128, T_SEQ / 128), 256, 0, stream>>>(aob, woT, d_out, QS, HID);
}

// Round 7
// 563.330 us; speedup vs baseline: 1.5096x; 1.0534x over previous
//
#include <hip/hip_runtime.h>

#define T_SEQ 2048
#define HID   4096
#define NH    32
#define NKV   8
#define HD    128
#define QS    (NH*HD)        // 4096
#define KVS   (NKV*HD)       // 1024
#define QKVN  (QS + 2*KVS)   // 6144

typedef unsigned short u16;
typedef __attribute__((ext_vector_type(8))) __bf16 bf16x8;
typedef __attribute__((ext_vector_type(8))) unsigned short u16x8;
typedef __attribute__((ext_vector_type(4))) unsigned short u16x4;
typedef __attribute__((ext_vector_type(4))) float f32x4;

__device__ __forceinline__ u16 f2bu(float x) {          // f32 -> bf16 (RNE)
  unsigned u = __builtin_bit_cast(unsigned, x);
  return (u16)((u + 0x7fffu + ((u >> 16) & 1u)) >> 16);
}
__device__ __forceinline__ float bu2f(u16 v) {
  unsigned u = ((unsigned)v) << 16;
  return __builtin_bit_cast(float, u);
}
__device__ __forceinline__ void gload16(const void* g, void* l) {
  __builtin_amdgcn_global_load_lds((const __attribute__((address_space(1))) void*)g,
                                   (__attribute__((address_space(3))) void*)l, 16, 0, 0);
}

// ---- merged prep: f32->bf16 convert of hs + transpose-converts of Wqkv, Wo ----
// blocks [0,2048): cvt; [2048,8192): wqkv 64x64 transpose tiles; [8192,12288): wo
__global__ void k_prep(const float* __restrict__ hs, const float* __restrict__ wqkv,
                       const float* __restrict__ wo, u16* __restrict__ hsb,
                       u16* __restrict__ wqkvT, u16* __restrict__ woT) {
  __shared__ float tile[64][65];
  const int b = blockIdx.x, tid = threadIdx.x;
  if (b < 2048) {                       // ---- cvt: 2 groups of 8 per thread ----
    int i = b * 256 + tid;
#pragma unroll
    for (int g = 0; g < 2; ++g, i += 524288) {
      const float4* p = (const float4*)hs + (size_t)i * 2;
      float4 a = p[0], bb = p[1];
      u16x8 v;
      v[0]=f2bu(a.x); v[1]=f2bu(a.y); v[2]=f2bu(a.z); v[3]=f2bu(a.w);
      v[4]=f2bu(bb.x); v[5]=f2bu(bb.y); v[6]=f2bu(bb.z); v[7]=f2bu(bb.w);
      *((u16x8*)hsb + i) = v;
    }
    return;
  }
  const float* in; u16* out; int R, C, bx, by;
  if (b < 8192) { in = wqkv; out = wqkvT; R = HID; C = QKVN; bx = (b - 2048) % 96; by = (b - 2048) / 96; }
  else          { in = wo;   out = woT;   R = QS;  C = HID;  bx = (b - 8192) % 64; by = (b - 8192) / 64; }
  const int c0 = bx * 64, r0 = by * 64;
  const int row = tid >> 2, c4 = (tid & 3) * 4;
#pragma unroll
  for (int j = 0; j < 4; ++j) {
    float4 a = *(const float4*)(in + (size_t)(r0 + row) * C + c0 + c4 + j * 16);
    tile[row][c4 + j * 16 + 0] = a.x;
    tile[row][c4 + j * 16 + 1] = a.y;
    tile[row][c4 + j * 16 + 2] = a.z;
    tile[row][c4 + j * 16 + 3] = a.w;
  }
  __syncthreads();
  const int col = tid >> 2, rq = (tid & 3) * 16;
  u16x8 v0, v1;
#pragma unroll
  for (int j = 0; j < 8; ++j) v0[j] = f2bu(tile[rq + j][col]);
#pragma unroll
  for (int j = 0; j < 8; ++j) v1[j] = f2bu(tile[rq + 8 + j][col]);
  u16* dst = out + (size_t)(c0 + col) * R + r0 + rq;
  *(u16x8*)(dst) = v0;
  *(u16x8*)(dst + 8) = v1;
}

// ------- bf16 GEMM: C[m,n] = sum_k A[m,k] * Bt[n,k]; C stride ldc -------
// 128x128 tile, BK=64, 4 waves (each 64x64), mfma_f32_16x16x32_bf16
template<int OUTF32>
__global__ __launch_bounds__(256, 2)
void k_gemm(const u16* __restrict__ A, const u16* __restrict__ Bt,
            void* __restrict__ C, int K, int ldc) {
  __shared__ u16 sA[128 * 64];
  __shared__ u16 sB[128 * 64];
  const int tid = threadIdx.x;
  const int w = tid >> 6, lane = tid & 63, lo = lane & 15, hi = lane >> 4;
  const int wr = w >> 1, wc = w & 1;
  const int bm = blockIdx.y * 128, bn = blockIdx.x * 128;
  f32x4 acc[4][4] = {};
  const int nk = K >> 6;
  for (int kt = 0; kt < nk; ++kt) {
    const int kbase = kt * 64;
#pragma unroll
    for (int i = 0; i < 4; ++i) {          // stage 16KB A + 16KB B
      int c = i * 256 + tid;
      int row = c >> 3, o8 = (c & 7) * 8;
      gload16(A + (size_t)(bm + row) * K + kbase + o8, sA + c * 8);
      gload16(Bt + (size_t)(bn + row) * K + kbase + o8, sB + c * 8);
    }
    __syncthreads();
#pragma unroll
    for (int kc = 0; kc < 2; ++kc) {
      bf16x8 af[4], bfr[4];
#pragma unroll
      for (int m = 0; m < 4; ++m)
        af[m] = *(const bf16x8*)(sA + (wr * 64 + m * 16 + lo) * 64 + kc * 32 + hi * 8);
#pragma unroll
      for (int n = 0; n < 4; ++n)
        bfr[n] = *(const bf16x8*)(sB + (wc * 64 + n * 16 + lo) * 64 + kc * 32 + hi * 8);
#pragma unroll
      for (int m = 0; m < 4; ++m)
#pragma unroll
        for (int n = 0; n < 4; ++n)
          acc[m][n] = __builtin_amdgcn_mfma_f32_16x16x32_bf16(af[m], bfr[n], acc[m][n], 0, 0, 0);
    }
    __syncthreads();
  }
#pragma unroll
  for (int m = 0; m < 4; ++m)
#pragma unroll
    for (int n = 0; n < 4; ++n) {
      int col = bn + wc * 64 + n * 16 + lo;
#pragma unroll
      for (int r = 0; r < 4; ++r) {
        int row = bm + wr * 64 + m * 16 + hi * 4 + r;
        float v = acc[m][n][r];
        if (OUTF32) ((float*)C)[(size_t)row * ldc + col] = v;
        else        ((u16*)C)[(size_t)row * ldc + col] = f2bu(v);
      }
    }
}

// -------- fused RMSNorm + RoPE; qkv[T][6144] -> q[h][t][d], k/v[kvh][t][d] --------
__global__ void k_normrope(const u16* __restrict__ qkv, const int* __restrict__ pos,
                           const float* __restrict__ qw, const float* __restrict__ kw,
                           u16* __restrict__ qb, u16* __restrict__ kb, u16* __restrict__ vb) {
  const int t = blockIdx.x;
  const int tid = threadIdx.x, w = tid >> 6, lane = tid & 63;
  const float p = (float)pos[t];
  const int d0 = lane * 2;
  const int j = d0 & 63;
  const float L2T_64 = 19.931568569324174f / 64.0f;   // log2(1e6)/64
  float ang0 = p * exp2f(-(float)j * L2T_64);
  float ang1 = p * exp2f(-(float)(j + 1) * L2T_64);
  float c0 = cosf(ang0), s0 = sinf(ang0);
  float c1 = cosf(ang1), s1 = sinf(ang1);
  const bool hiHalf = lane >= 32;
  for (int it = 0; it < 10; ++it) {
    int h = it * 4 + w;                        // 0..39 (32 q heads + 8 k heads)
    bool isq = h < NH;
    int base = t * QKVN + (isq ? h * HD : QS + (h - NH) * HD);
    float x0 = bu2f(qkv[base + d0]);
    float x1 = bu2f(qkv[base + d0 + 1]);
    float ss = x0 * x0 + x1 * x1;
#pragma unroll
    for (int off = 1; off < 64; off <<= 1) ss += __shfl_xor(ss, off);
    float inv = rsqrtf(ss * (1.0f / 128.0f) + 1e-6f);
    const float* nw = isq ? qw : kw;
    float y0 = x0 * inv * nw[d0];
    float y1 = x1 * inv * nw[d0 + 1];
    float z0 = __shfl_xor(y0, 32);             // partner element (d +/- 64)
    float z1 = __shfl_xor(y1, 32);
    float r0 = hiHalf ? (y0 * c0 + z0 * s0) : (y0 * c0 - z0 * s0);
    float r1 = hiHalf ? (y1 * c1 + z1 * s1) : (y1 * c1 - z1 * s1);
    u16* dst = isq ? (qb + ((size_t)h * T_SEQ + t) * HD)
                   : (kb + ((size_t)(h - NH) * T_SEQ + t) * HD);
    dst[d0] = f2bu(r0);
    dst[d0 + 1] = f2bu(r1);
  }
  for (int i = tid; i < KVS; i += 256) {       // v: plain cast copy
    int kvh = i >> 7, d = i & 127;
    vb[((size_t)kvh * T_SEQ + t) * HD + d] = qkv[t * QKVN + QS + KVS + i];
  }
}

// ---------------- causal GQA flash attention (v4: dbuf async staging) ----------------
// block = (pair {xb, 31-xb}, head); 4 waves x 16 q rows; KV tile 64; K/V double-
// buffered: K(t+1) via global_load_lds + V(t+1) via reg loads issued BEFORE the
// compute of tile t; V written to LDS after compute; ONE barrier per iteration.
// LDS 16B-group XOR swizzle on all tiles (inverse swizzle on K's global source).
__global__ __launch_bounds__(256, 2)
void k_attn(const u16* __restrict__ qb, const u16* __restrict__ kb,
            const u16* __restrict__ vb, u16* __restrict__ ao) {
  __shared__ u16 Ks[2][64 * 128];    // [kv][feat]  (swizzled groups)
  __shared__ u16 Vt[2][128 * 64];    // [feat][kv]  (swizzled groups)
  __shared__ u16 Ps[4][16 * 64];     // per-wave P  (swizzled groups)
  const int h = blockIdx.y, kvh = h >> 2;
  const int tid = threadIdx.x, w = tid >> 6, lane = tid & 63, lo = lane & 15, hi = lane >> 4;
  const int lo7 = lane & 7;
  const float scale = 0.08838834764831845f;   // 1/sqrt(128)
  const u16* Kb = kb + (size_t)kvh * T_SEQ * HD;
  const u16* Vb = vb + (size_t)kvh * T_SEQ * HD;
  const int krow = tid >> 4;                       // 0..15
  const int kg = (tid & 15) ^ (krow & 7);          // inverse-swizzled src group
  const int vkvc = tid & 15, vfc = tid >> 4;       // V transpose coords

  for (int item = 0; item < 2; ++item) {
    const int xb = item == 0 ? (int)blockIdx.x : 31 - (int)blockIdx.x;
    const int q0 = xb * 64;
    const int nkt = xb + 1;
    const int qr0 = q0 + w * 16;
    bf16x8 qf[4];
    const u16* Qp = qb + ((size_t)h * T_SEQ + qr0 + lo) * HD;
#pragma unroll
    for (int kc = 0; kc < 4; ++kc) qf[kc] = *(const bf16x8*)(Qp + kc * 32 + hi * 8);
    f32x4 o[8] = {};
    float mrow[4], ssum[4];
#pragma unroll
    for (int r = 0; r < 4; ++r) { mrow[r] = -1e30f; ssum[r] = 0.f; }

    u16x8 vv[4];
    // ---- prologue: stage tile 0 into slot 0 (V loads first, K gloads after) ----
#pragma unroll
    for (int r4 = 0; r4 < 4; ++r4)
      vv[r4] = *(const u16x8*)(Vb + (size_t)(vkvc * 4 + r4) * HD + vfc * 8);
#pragma unroll
    for (int i = 0; i < 4; ++i)
      gload16(Kb + (size_t)(i * 16 + krow) * HD + kg * 8, Ks[0] + i * 2048 + tid * 8);
#pragma unroll
    for (int e = 0; e < 8; ++e) {
      int feat = vfc * 8 + e;
      int gp = (vkvc >> 1) ^ (feat & 7);
      u16x4 pk; pk[0] = vv[0][e]; pk[1] = vv[1][e]; pk[2] = vv[2][e]; pk[3] = vv[3][e];
      *(u16x4*)(Vt[0] + feat * 64 + gp * 8 + (vkvc & 1) * 4) = pk;
    }
    __syncthreads();                 // drains K(0) gloads (compiler vmcnt(0))

    for (int kt = 0; kt < nkt; ++kt) {
      const int cur = kt & 1;
      const bool pf = (kt + 1 < nkt);
      if (pf) {                      // ---- issue next-tile staging early ----
#pragma unroll
        for (int r4 = 0; r4 < 4; ++r4)
          vv[r4] = *(const u16x8*)(Vb + (size_t)((kt + 1) * 64 + vkvc * 4 + r4) * HD + vfc * 8);
#pragma unroll
        for (int i = 0; i < 4; ++i)
          gload16(Kb + (size_t)((kt + 1) * 64 + i * 16 + krow) * HD + kg * 8,
                  Ks[cur ^ 1] + i * 2048 + tid * 8);
      }
      // ---- QK^T: 4 n-tiles of 16 kv ----
      f32x4 sa[4] = {};
#pragma unroll
      for (int kc = 0; kc < 4; ++kc) {
#pragma unroll
        for (int n = 0; n < 4; ++n) {
          int row = n * 16 + lo;
          bf16x8 kf = *(const bf16x8*)(Ks[cur] + row * 128 + (((kc * 4 + hi) ^ lo7) * 8));
          sa[n] = __builtin_amdgcn_mfma_f32_16x16x32_bf16(qf[kc], kf, sa[n], 0, 0, 0);
        }
      }
      // ---- mask + online softmax ----
      float pvv[4][4], pmax[4];
#pragma unroll
      for (int r = 0; r < 4; ++r) {
        int qi = qr0 + hi * 4 + r;
        float pm = -1e30f;
#pragma unroll
        for (int n = 0; n < 4; ++n) {
          int kj = kt * 64 + n * 16 + lo;
          float sv = (kj <= qi) ? sa[n][r] * scale : -1e30f;
          pvv[n][r] = sv;
          pm = fmaxf(pm, sv);
        }
#pragma unroll
        for (int off = 1; off < 16; off <<= 1) pm = fmaxf(pm, __shfl_xor(pm, off));
        pmax[r] = pm;
      }
#pragma unroll
      for (int r = 0; r < 4; ++r) {
        float mnew = fmaxf(mrow[r], pmax[r]);
        float corr = __expf(mrow[r] - mnew);
        mrow[r] = mnew;
        float ps = 0.f;
#pragma unroll
        for (int n = 0; n < 4; ++n) {
          float p = __expf(pvv[n][r] - mnew);
          pvv[n][r] = p; ps += p;
        }
#pragma unroll
        for (int off = 1; off < 16; off <<= 1) ps += __shfl_xor(ps, off);
        ssum[r] = ssum[r] * corr + ps;
#pragma unroll
        for (int nf = 0; nf < 8; ++nf) o[nf][r] *= corr;
      }
      // ---- P -> LDS (swizzled), wave-local ----
      u16* Pw = Ps[w];
#pragma unroll
      for (int n = 0; n < 4; ++n) {
        int gcol = n * 2 + (lo >> 3);
#pragma unroll
        for (int r = 0; r < 4; ++r) {
          int row = hi * 4 + r;
          Pw[row * 64 + ((gcol ^ (row & 7)) * 8) + lo7] = f2bu(pvv[n][r]);
        }
      }
      // ---- PV ----
#pragma unroll
      for (int ks = 0; ks < 2; ++ks) {
        bf16x8 pfr = *(const bf16x8*)(Pw + lo * 64 + (((ks * 4 + hi) ^ lo7) * 8));
#pragma unroll
        for (int nf = 0; nf < 8; ++nf) {
          int feat = nf * 16 + lo;
          bf16x8 vf = *(const bf16x8*)(Vt[cur] + feat * 64 + (((ks * 4 + hi) ^ lo7) * 8));
          o[nf] = __builtin_amdgcn_mfma_f32_16x16x32_bf16(pfr, vf, o[nf], 0, 0, 0);
        }
      }
      if (pf) {                      // ---- V(t+1) regs -> LDS (other slot) ----
#pragma unroll
        for (int e = 0; e < 8; ++e) {
          int feat = vfc * 8 + e;
          int gp = (vkvc >> 1) ^ (feat & 7);
          u16x4 pk; pk[0] = vv[0][e]; pk[1] = vv[1][e]; pk[2] = vv[2][e]; pk[3] = vv[3][e];
          *(u16x4*)(Vt[cur ^ 1] + feat * 64 + gp * 8 + (vkvc & 1) * 4) = pk;
        }
      }
      __syncthreads();               // single barrier per iteration
    }
#pragma unroll
    for (int r = 0; r < 4; ++r) ssum[r] = 1.0f / ssum[r];
#pragma unroll
    for (int nf = 0; nf < 8; ++nf)
#pragma unroll
      for (int r = 0; r < 4; ++r) {
        int row = qr0 + hi * 4 + r;
        ao[(size_t)row * HID + h * HD + nf * 16 + lo] = f2bu(o[nf][r] * ssum[r]);
      }
  }
}

// ---------------- launch ----------------
// d_out is FLOAT32 (32 MiB): bf16 scratch for hsb (lower half) + qbuf (upper
// half) until the final f32 GEMM overwrites it. Workspace peak: 112 MiB.
extern "C" void kernel_launch(void* const* d_in, const int* in_sizes, int n_in,
                              void* d_out, int out_size, void* d_ws, size_t ws_size,
                              hipStream_t stream) {
  (void)in_sizes; (void)n_in; (void)out_size; (void)ws_size;
  const int*   positions = (const int*)d_in[0];
  const float* hs   = (const float*)d_in[1];
  const float* wqkv = (const float*)d_in[2];
  const float* wo   = (const float*)d_in[3];
  const float* qnw  = (const float*)d_in[4];
  const float* knw  = (const float*)d_in[5];
  char* ws = (char*)d_ws;

  u16* hsb   = (u16*)d_out;                     // 16 MiB (d_out lower half)
  u16* qbuf  = (u16*)d_out + 8388608;           // 16 MiB (d_out upper half)
  u16* wqkvT = (u16*)(ws + 0);                  // 48 MiB
  u16* woT   = (u16*)(ws + 50331648);           // 32 MiB
  u16* qkvb  = (u16*)(ws + 83886080);           // 24 MiB
  u16* kbuf  = (u16*)(ws + 109051904);          //  4 MiB
  u16* vbuf  = (u16*)(ws + 113246208);          //  4 MiB (ends 117440512)
  u16* aob   = (u16*)(ws + 0);                  // 16 MiB (reuses dead wqkvT)

  k_prep<<<12288, 256, 0, stream>>>(hs, wqkv, wo, hsb, wqkvT, woT);
  k_gemm<0><<<dim3(QKVN / 128, T_SEQ / 128), 256, 0, stream>>>(hsb, wqkvT, qkvb, HID, QKVN);
  k_normrope<<<T_SEQ, 256, 0, stream>>>(qkvb, positions, qnw, knw, qbuf, kbuf, vbuf);
  k_attn<<<dim3(16, NH), 256, 0, stream>>>(qbuf, kbuf, vbuf, aob);
  k_gemm<1><<<dim3(HID / 128, T_SEQ / 128), 256, 0, stream>>>(aob, woT, d_out, QS, HID);
}